// Round 15
// baseline (201.132 us; speedup 1.0000x reference)
//
#include <hip/hip_runtime.h>
#include <hip/hip_bf16.h>
#include <string.h>

// MHA B=2,S=2048,D=1024,H=16,Hd=64. Inputs fp32, output fp32.
// R28 (resubmit; R14 bench was a GPU-acquisition infra failure, kernel
// never ran). Revert to R24-exact (best measured 197.8us: reg-staged
// z-split GEMMs + split-K attn; R27's global_load_lds GEMM restage was
// null) and add T1 XCD-swizzle to attn's block mapping: bijective
// nl=(lin%8)*64+lin/8 gives each XCD 4 complete bh's (2MB K/V <= 4MB L2),
// attacking the measured ~4x K/V HBM refetch (FETCH 71MB vs ~32 ideal).
// All else bit-identical to R24.

#define DM 1024
#define S_LEN 2048
#define NH 16
#define HD 64

using u16 = unsigned short;
using u32 = unsigned int;

typedef short bf16x8 __attribute__((ext_vector_type(8)));
typedef float f32x4  __attribute__((ext_vector_type(4)));
typedef float f32x16 __attribute__((ext_vector_type(16)));
typedef unsigned int u32x2 __attribute__((ext_vector_type(2)));

__device__ __forceinline__ u16 f2bf(float f) {
    u32 i = __float_as_uint(f);
    u32 r = i + 0x7fffu + ((i >> 16) & 1u);  // RNE
    return (u16)(r >> 16);
}
__device__ __forceinline__ u32 pk_bf16(float a, float b) {  // low16=a, high16=b (RNE)
    __hip_bfloat162 h = __float22bfloat162_rn(float2{a, b});
    u32 r; memcpy(&r, &h, 4);
    return r;
}

// ---- prep: x fp32 -> bf16 ----
__global__ __launch_bounds__(256) void prep_x(const float* __restrict__ X, u16* __restrict__ out) {
    int i = (blockIdx.x * 256 + threadIdx.x) * 4;
    float4 v = *(const float4*)(X + i);
    *(uint2*)(out + i) = make_uint2(pk_bf16(v.x, v.y), pk_bf16(v.z, v.w));
}

// ---- prep: W fp32 [K][N] -> W^T bf16 [N][K] ----
__global__ __launch_bounds__(256) void prep_wt3(
    const float* __restrict__ W0, const float* __restrict__ W1, const float* __restrict__ W2,
    u16* __restrict__ T0, u16* __restrict__ T1, u16* __restrict__ T2)
{
    __shared__ u16 tile[64][72];
    const float* W = (blockIdx.z == 0) ? W0 : (blockIdx.z == 1) ? W1 : W2;
    u16* WT        = (blockIdx.z == 0) ? T0 : (blockIdx.z == 1) ? T1 : T2;
    const int t = threadIdx.x;
    const int n0 = blockIdx.x * 64, k0 = blockIdx.y * 64;
    #pragma unroll
    for (int it = 0; it < 4; it++) {
        int k = it * 16 + (t >> 4);
        int n = (t & 15) * 4;
        float4 v = *(const float4*)(W + (size_t)(k0 + k) * DM + n0 + n);
        tile[n + 0][k] = f2bf(v.x);
        tile[n + 1][k] = f2bf(v.y);
        tile[n + 2][k] = f2bf(v.z);
        tile[n + 3][k] = f2bf(v.w);
    }
    __syncthreads();
    int n = t >> 2, kg = (t & 3) * 16;
    uint4 a = *(const uint4*)&tile[n][kg];
    uint4 b = *(const uint4*)&tile[n][kg + 8];
    *(uint4*)(WT + (size_t)(n0 + n) * DM + k0 + kg)     = a;
    *(uint4*)(WT + (size_t)(n0 + n) * DM + k0 + kg + 8) = b;
}

__global__ __launch_bounds__(256) void prep_wt1(const float* __restrict__ W, u16* __restrict__ WT) {
    __shared__ u16 tile[64][72];
    const int t = threadIdx.x;
    const int n0 = blockIdx.x * 64, k0 = blockIdx.y * 64;
    #pragma unroll
    for (int it = 0; it < 4; it++) {
        int k = it * 16 + (t >> 4);
        int n = (t & 15) * 4;
        float4 v = *(const float4*)(W + (size_t)(k0 + k) * DM + n0 + n);
        tile[n + 0][k] = f2bf(v.x);
        tile[n + 1][k] = f2bf(v.y);
        tile[n + 2][k] = f2bf(v.z);
        tile[n + 3][k] = f2bf(v.w);
    }
    __syncthreads();
    int n = t >> 2, kg = (t & 3) * 16;
    uint4 a = *(const uint4*)&tile[n][kg];
    uint4 b = *(const uint4*)&tile[n][kg + 8];
    *(uint4*)(WT + (size_t)(n0 + n) * DM + k0 + kg)     = a;
    *(uint4*)(WT + (size_t)(n0 + n) * DM + k0 + kg + 8) = b;
}

// ---- QKV projection, z-split: blockIdx.z selects Q/K/V. 128x128 tile,
// ---- BK=64, 4 waves each computing 64x64. 3 blocks/CU. (R23/R24-exact) ----
__global__ __launch_bounds__(256, 3) void gemm_qkv_z(
    const u16* __restrict__ WQT, const u16* __restrict__ WKT, const u16* __restrict__ WVT,
    const u16* __restrict__ X,
    const float* __restrict__ bq, const float* __restrict__ bk, const float* __restrict__ bv,
    u16* __restrict__ outQ, u16* __restrict__ outK, u16* __restrict__ outVT)
{
    __shared__ u16 Ws[128][72];
    __shared__ u16 Xs[128][72];

    const int z = blockIdx.z;
    const u16* WT = (z == 0) ? WQT : (z == 1) ? WKT : WVT;

    const int t = threadIdx.x;
    const int w = t >> 6, lane = t & 63, quad = lane >> 4, l16 = lane & 15;
    const int Mb0 = blockIdx.x * 128;
    const int Nb0 = blockIdx.y * 128;
    const int mloc = (w & 1) * 64, nloc = (w >> 1) * 64;

    f32x4 acc[4][4];
    #pragma unroll
    for (int i = 0; i < 4; i++)
        #pragma unroll
        for (int j = 0; j < 4; j++) acc[i][j] = (f32x4){0.f, 0.f, 0.f, 0.f};

    const int sr = t >> 3, sc8 = (t & 7) * 8;

    for (int k0 = 0; k0 < DM; k0 += 64) {
        __syncthreads();
        #pragma unroll
        for (int i = 0; i < 4; i++) {
            int r = i * 32 + sr;
            *(uint4*)&Ws[r][sc8] = *(const uint4*)(WT + (size_t)(Mb0 + r) * DM + k0 + sc8);
            *(uint4*)&Xs[r][sc8] = *(const uint4*)(X  + (size_t)(Nb0 + r) * DM + k0 + sc8);
        }
        __syncthreads();

        #pragma unroll
        for (int ks = 0; ks < 2; ks++) {
            const int kk = ks * 32 + quad * 8;
            bf16x8 af[4], bf[4];
            #pragma unroll
            for (int mt = 0; mt < 4; mt++)
                af[mt] = *(const bf16x8*)&Ws[mloc + mt * 16 + l16][kk];
            #pragma unroll
            for (int nt = 0; nt < 4; nt++)
                bf[nt] = *(const bf16x8*)&Xs[nloc + nt * 16 + l16][kk];
            #pragma unroll
            for (int mt = 0; mt < 4; mt++)
                #pragma unroll
                for (int nt = 0; nt < 4; nt++)
                    acc[mt][nt] = __builtin_amdgcn_mfma_f32_16x16x32_bf16(af[mt], bf[nt], acc[mt][nt], 0, 0, 0);
        }
    }

    const float QS = 0.18033688f;  // 0.125 * log2(e): attn uses raw v_exp (2^x)
    if (z <= 1) {
        u16* outP = (z == 0) ? outQ : outK;
        const float* bias = (z == 0) ? bq : bk;
        const float scale = (z == 0) ? QS : 1.0f;
        #pragma unroll
        for (int mt = 0; mt < 4; mt++) {
            int nf0 = Mb0 + mloc + mt * 16 + quad * 4;
            int hh = nf0 >> 6, hd = nf0 & 63;
            float4 bb = *(const float4*)(bias + nf0);
            #pragma unroll
            for (int nt = 0; nt < 4; nt++) {
                int m = Nb0 + nloc + nt * 16 + l16;
                int b = m >> 11, s = m & 2047;
                size_t idx = (size_t)(b * NH + hh) * 131072 + (size_t)s * 64 + hd;
                *(uint2*)(outP + idx) = make_uint2(
                    pk_bf16((acc[mt][nt][0] + bb.x) * scale, (acc[mt][nt][1] + bb.y) * scale),
                    pk_bf16((acc[mt][nt][2] + bb.z) * scale, (acc[mt][nt][3] + bb.w) * scale));
            }
        }
    } else {
        #pragma unroll
        for (int mt = 0; mt < 4; mt++) {
            #pragma unroll
            for (int r = 0; r < 4; r++) {
                int nf = Mb0 + mloc + mt * 16 + quad * 4 + r;
                int hh = nf >> 6, hd = nf & 63;
                float bb = bv[nf];
                #pragma unroll
                for (int nt = 0; nt < 4; nt++) {
                    int m = Nb0 + nloc + nt * 16 + l16;
                    int b = m >> 11, s = m & 2047;
                    outVT[(size_t)(b * NH + hh) * 131072 + (size_t)hd * S_LEN + s]
                        = f2bf(acc[mt][nt][r] + bb);
                }
            }
        }
    }
}

// ---- out GEMM, LDS-staged. Block: 64 feat x 128 tok, BK=64. (R24-exact) ----
__global__ __launch_bounds__(256) void gemm_out(
    const u16* __restrict__ A, const u16* __restrict__ B,
    const float* __restrict__ bias, float* __restrict__ of32)
{
    __shared__ u16 As[64][72];
    __shared__ u16 Bs[128][72];

    const int t = threadIdx.x;
    const int w = t >> 6, lane = t & 63, quad = lane >> 4, l16 = lane & 15;
    const int Mb0 = blockIdx.x * 64;
    const int Nb0 = blockIdx.y * 128;
    const int Mb = Mb0 + (w & 1) * 32;
    const int Nb = Nb0 + (w >> 1) * 64;
    const int mloc = (w & 1) * 32, nloc = (w >> 1) * 64;

    f32x4 acc[2][4];
    #pragma unroll
    for (int i = 0; i < 2; i++)
        #pragma unroll
        for (int j = 0; j < 4; j++) acc[i][j] = (f32x4){0.f, 0.f, 0.f, 0.f};

    const int sr = t >> 3, sc8 = (t & 7) * 8;

    for (int k0 = 0; k0 < DM; k0 += 64) {
        const int h = k0 >> 6;
        __syncthreads();
        #pragma unroll
        for (int i = 0; i < 2; i++) {
            int r = i * 32 + sr;
            *(uint4*)&As[r][sc8] = *(const uint4*)(A + (size_t)(Mb0 + r) * DM + k0 + sc8);
        }
        #pragma unroll
        for (int i = 0; i < 4; i++) {
            int r = i * 32 + sr;
            int m = Nb0 + r;
            int b = m >> 11, s = m & 2047;
            *(uint4*)&Bs[r][sc8] =
                *(const uint4*)(B + (size_t)(b * NH + h) * 131072 + (size_t)s * 64 + sc8);
        }
        __syncthreads();

        #pragma unroll
        for (int ks = 0; ks < 2; ks++) {
            const int kk = ks * 32 + quad * 8;
            bf16x8 a0 = *(const bf16x8*)&As[mloc + l16][kk];
            bf16x8 a1 = *(const bf16x8*)&As[mloc + 16 + l16][kk];
            #pragma unroll
            for (int nt = 0; nt < 4; nt++) {
                bf16x8 bf = *(const bf16x8*)&Bs[nloc + nt * 16 + l16][kk];
                acc[0][nt] = __builtin_amdgcn_mfma_f32_16x16x32_bf16(a0, bf, acc[0][nt], 0, 0, 0);
                acc[1][nt] = __builtin_amdgcn_mfma_f32_16x16x32_bf16(a1, bf, acc[1][nt], 0, 0, 0);
            }
        }
    }
    #pragma unroll
    for (int mt = 0; mt < 2; mt++) {
        int nf0 = Mb + mt * 16 + quad * 4;
        float4 bvv = *(const float4*)(bias + nf0);
        #pragma unroll
        for (int nt = 0; nt < 4; nt++) {
            int m = Nb + nt * 16 + l16;
            float4 o;
            o.x = acc[mt][nt][0] + bvv.x; o.y = acc[mt][nt][1] + bvv.y;
            o.z = acc[mt][nt][2] + bvv.z; o.w = acc[mt][nt][3] + bvv.w;
            *(float4*)(of32 + (size_t)m * DM + nf0) = o;
        }
    }
}

// ---- attention: in-block split-K (R24-exact) + T1 XCD-swizzle on the
// ---- block mapping: nl=(lin%8)*64+lin/8 (bijective, 512%8==0) so each
// ---- XCD owns 4 complete bh's -> K/V 2MB fits its 4MB L2. ----
__global__ __launch_bounds__(512, 4) void attn_mfma(
    const u16* __restrict__ Q, const u16* __restrict__ K, const u16* __restrict__ VT,
    u16* __restrict__ O)
{
    __shared__ __align__(64) u16 smem[2][2][2][64][72];

    const int t = threadIdx.x;
    const int w = t >> 6, lane = t & 63;
    const int wq = w & 3, half = w >> 2;
    const int l32 = lane & 31, h = lane >> 5;

    // XCD swizzle: dispatch-linear id -> (q-tile, bh) so XCD i gets bh [4i,4i+4)
    const int lin = blockIdx.y * 16 + blockIdx.x;      // gridDim.x == 16
    const int nl  = (lin & 7) * 64 + (lin >> 3);       // bijective on [0,512)
    const int bh  = nl >> 4;
    const int q0  = (nl & 15) * 128;
    const size_t base = (size_t)bh * 131072;

    const int qrow = q0 + wq * 32 + l32;
    bf16x8 qf[4];
    #pragma unroll
    for (int ks = 0; ks < 4; ks++)
        qf[ks] = *(const bf16x8*)(Q + base + (size_t)qrow * 64 + ks * 16 + h * 8);

    const short onebf = (short)0x3F80;
    const bf16x8 ones = {onebf, onebf, onebf, onebf, onebf, onebf, onebf, onebf};

    f32x16 o[2], lacc;
    #pragma unroll
    for (int ht = 0; ht < 2; ht++)
        #pragma unroll
        for (int i = 0; i < 16; i++) o[ht][i] = 0.f;
    #pragma unroll
    for (int i = 0; i < 16; i++) lacc[i] = 0.f;

    const int sr = t >> 3;            // 0..63
    const int sc8 = (t & 7) * 8;      // u16 col
    const u16* Kg = K + base;
    const u16* Vg = VT + base;

    *(uint4*)&smem[0][0][0][sr][sc8] = *(const uint4*)(Kg + (size_t)sr * 64 + sc8);
    *(uint4*)&smem[0][1][0][sr][sc8] = *(const uint4*)(Kg + (size_t)(16 * 64 + sr) * 64 + sc8);
    *(uint4*)&smem[1][0][0][sr][sc8] = *(const uint4*)(Vg + (size_t)sr * S_LEN + sc8);
    *(uint4*)&smem[1][1][0][sr][sc8] = *(const uint4*)(Vg + (size_t)sr * S_LEN + 16 * 64 + sc8);
    __syncthreads();

    for (int it = 0; it < 16; it++) {
        const int cur = it & 1;
        uint4 kra, krb, vra, vrb;
        if (it < 15) {
            kra = *(const uint4*)(Kg + (size_t)((it + 1) * 64 + sr) * 64 + sc8);
            krb = *(const uint4*)(Kg + (size_t)((it + 17) * 64 + sr) * 64 + sc8);
            vra = *(const uint4*)(Vg + (size_t)sr * S_LEN + (it + 1) * 64 + sc8);
            vrb = *(const uint4*)(Vg + (size_t)sr * S_LEN + (it + 17) * 64 + sc8);
        }

        const u16 (*Ksc)[72] = smem[0][half][cur];
        const u16 (*Vsc)[72] = smem[1][half][cur];

        #pragma unroll
        for (int kh = 0; kh < 2; kh++) {
            f32x16 s;
            #pragma unroll
            for (int i = 0; i < 16; i++) s[i] = 0.f;
            #pragma unroll
            for (int ks = 0; ks < 4; ks++) {
                bf16x8 kf = *(const bf16x8*)&Ksc[kh * 32 + l32][ks * 16 + h * 8];
                s = __builtin_amdgcn_mfma_f32_32x32x16_bf16(kf, qf[ks], s, 0, 0, 0);
            }
            float p[16];
            #pragma unroll
            for (int i = 0; i < 16; i++) p[i] = __builtin_amdgcn_exp2f(s[i]);
            u32 A0 = pk_bf16(p[0],  p[1]),  B0 = pk_bf16(p[2],  p[3]);
            u32 A1 = pk_bf16(p[4],  p[5]),  B1 = pk_bf16(p[6],  p[7]);
            u32 A2 = pk_bf16(p[8],  p[9]),  B2 = pk_bf16(p[10], p[11]);
            u32 A3 = pk_bf16(p[12], p[13]), B3 = pk_bf16(p[14], p[15]);
            u32x2 sA0 = __builtin_amdgcn_permlane32_swap(A0, A1, false, false);
            u32x2 sB0 = __builtin_amdgcn_permlane32_swap(B0, B1, false, false);
            u32x2 sA1 = __builtin_amdgcn_permlane32_swap(A2, A3, false, false);
            u32x2 sB1 = __builtin_amdgcn_permlane32_swap(B2, B3, false, false);
            union { bf16x8 v; u32 wd[4]; } fr0, fr1;
            fr0.wd[0] = sA0.x; fr0.wd[1] = sB0.x; fr0.wd[2] = sA0.y; fr0.wd[3] = sB0.y;
            fr1.wd[0] = sA1.x; fr1.wd[1] = sB1.x; fr1.wd[2] = sA1.y; fr1.wd[3] = sB1.y;

            lacc = __builtin_amdgcn_mfma_f32_32x32x16_bf16(fr0.v, ones, lacc, 0, 0, 0);
            lacc = __builtin_amdgcn_mfma_f32_32x32x16_bf16(fr1.v, ones, lacc, 0, 0, 0);

            #pragma unroll
            for (int ht = 0; ht < 2; ht++) {
                bf16x8 vf0 = *(const bf16x8*)&Vsc[ht * 32 + l32][kh * 32 + h * 8];
                o[ht] = __builtin_amdgcn_mfma_f32_32x32x16_bf16(fr0.v, vf0, o[ht], 0, 0, 0);
                bf16x8 vf1 = *(const bf16x8*)&Vsc[ht * 32 + l32][kh * 32 + 16 + h * 8];
                o[ht] = __builtin_amdgcn_mfma_f32_32x32x16_bf16(fr1.v, vf1, o[ht], 0, 0, 0);
            }
        }

        if (it < 15) {
            *(uint4*)&smem[0][0][cur ^ 1][sr][sc8] = kra;
            *(uint4*)&smem[0][1][cur ^ 1][sr][sc8] = krb;
            *(uint4*)&smem[1][0][cur ^ 1][sr][sc8] = vra;
            *(uint4*)&smem[1][1][cur ^ 1][sr][sc8] = vrb;
        }
        __syncthreads();
    }

    float* red = (float*)&smem[0][0][0][0][0];
    if (half) {
        #pragma unroll
        for (int i = 0; i < 16; i++) {
            red[((0 + wq) * 16 + i) * 64 + lane] = o[0][i];
            red[((4 + wq) * 16 + i) * 64 + lane] = o[1][i];
            red[((8 + wq) * 16 + i) * 64 + lane] = lacc[i];
        }
    }
    __syncthreads();
    if (!half) {
        #pragma unroll
        for (int i = 0; i < 16; i++) {
            o[0][i] += red[((0 + wq) * 16 + i) * 64 + lane];
            o[1][i] += red[((4 + wq) * 16 + i) * 64 + lane];
            lacc[i] += red[((8 + wq) * 16 + i) * 64 + lane];
        }
        float inv[16];
        #pragma unroll
        for (int r = 0; r < 16; r++) inv[r] = 1.0f / lacc[r];
        #pragma unroll
        for (int ht = 0; ht < 2; ht++)
            #pragma unroll
            for (int r = 0; r < 16; r++) {
                int q = q0 + wq * 32 + (r & 3) + 8 * (r >> 2) + 4 * h;
                O[base + (size_t)q * 64 + ht * 32 + l32] = f2bf(o[ht][r] * inv[r]);
            }
    }
}

extern "C" void kernel_launch(void* const* d_in, const int* in_sizes, int n_in,
                              void* d_out, int out_size, void* d_ws, size_t ws_size,
                              hipStream_t stream) {
    const float* x  = (const float*)d_in[0];
    const float* Wq = (const float*)d_in[1];
    const float* bq = (const float*)d_in[2];
    const float* Wk = (const float*)d_in[3];
    const float* bk = (const float*)d_in[4];
    const float* Wv = (const float*)d_in[5];
    const float* bv = (const float*)d_in[6];
    const float* Wo = (const float*)d_in[7];
    const float* bo = (const float*)d_in[8];
    float* out = (float*)d_out;

    // d_out as scratch during prep+proj (dead until final GEMM)
    u16* xbf = (u16*)d_out;
    u16* wqt = xbf + 4194304;
    u16* wkt = wqt + 1048576;
    u16* wvt = wkt + 1048576;

    u16* qws  = (u16*)d_ws;               // Q, later attnout (head layout)
    u16* kws  = qws + 4194304;            // K head layout; later Wo^T
    u16* vtws = kws + 4194304;            // V^T [bh][hd][s]
    u16* wot  = kws;

    prep_x<<<4096, 256, 0, stream>>>(x, xbf);
    prep_wt3<<<dim3(16, 16, 3), 256, 0, stream>>>(Wq, Wk, Wv, wqt, wkt, wvt);

    gemm_qkv_z<<<dim3(8, 32, 3), 256, 0, stream>>>(wqt, wkt, wvt, xbf, bq, bk, bv,
                                                   qws, kws, vtws);

    attn_mfma<<<dim3(16, 32), 512, 0, stream>>>(qws, kws, vtws, qws);

    prep_wt1<<<dim3(16, 16), 256, 0, stream>>>(Wo, wot);
    gemm_out<<<dim3(16, 32), 256, 0, stream>>>(wot, qws, bo, out);
}

// Round 17
// 196.349 us; speedup vs baseline: 1.0244x; 1.0244x over previous
//
#include <hip/hip_runtime.h>
#include <hip/hip_bf16.h>
#include <string.h>

// MHA B=2,S=2048,D=1024,H=16,Hd=64. Inputs fp32, output fp32.
// R29 (resubmit; R16 bench was a GPU-acquisition infra failure, kernel
// never ran). R24-exact compute kernels (best measured 197.8us; R28's
// attn XCD swizzle cut FETCH 71->13.6MB but was time-null-to-negative --
// L3-fit, m160 precedent -- reverted). One change: prep_x + prep_wt3
// merged into a single prep_all launch (z=0..2 W transposes, z=3..4 x
// conversion, 512 grid-stride blocks), 6 -> 5 kernels in the graph.
// prep_wt1 stays post-attn (wot aliases kws which holds K until attn
// completes).

#define DM 1024
#define S_LEN 2048
#define NH 16
#define HD 64

using u16 = unsigned short;
using u32 = unsigned int;

typedef short bf16x8 __attribute__((ext_vector_type(8)));
typedef float f32x4  __attribute__((ext_vector_type(4)));
typedef float f32x16 __attribute__((ext_vector_type(16)));
typedef unsigned int u32x2 __attribute__((ext_vector_type(2)));

__device__ __forceinline__ u16 f2bf(float f) {
    u32 i = __float_as_uint(f);
    u32 r = i + 0x7fffu + ((i >> 16) & 1u);  // RNE
    return (u16)(r >> 16);
}
__device__ __forceinline__ u32 pk_bf16(float a, float b) {  // low16=a, high16=b (RNE)
    __hip_bfloat162 h = __float22bfloat162_rn(float2{a, b});
    u32 r; memcpy(&r, &h, 4);
    return r;
}

// ---- merged prep: z=0..2 -> Wq/Wk/Wv transpose+convert; z=3..4 -> x convert ----
__global__ __launch_bounds__(256) void prep_all(
    const float* __restrict__ W0, const float* __restrict__ W1, const float* __restrict__ W2,
    const float* __restrict__ X,
    u16* __restrict__ T0, u16* __restrict__ T1, u16* __restrict__ T2,
    u16* __restrict__ xout)
{
    __shared__ u16 tile[64][72];
    const int z = blockIdx.z;
    const int t = threadIdx.x;

    if (z >= 3) {
        // x fp32 -> bf16: 512 blocks x 256 thr x 4 elems x 8 iters = 4,194,304
        const int lin = ((z - 3) * 16 + blockIdx.y) * 16 + blockIdx.x;  // [0,512)
        const int base = (lin * 256 + t) * 4;
        #pragma unroll
        for (int i = 0; i < 8; i++) {
            int idx = base + i * 524288;
            float4 v = *(const float4*)(X + idx);
            *(uint2*)(xout + idx) = make_uint2(pk_bf16(v.x, v.y), pk_bf16(v.z, v.w));
        }
        return;
    }

    const float* W = (z == 0) ? W0 : (z == 1) ? W1 : W2;
    u16* WT        = (z == 0) ? T0 : (z == 1) ? T1 : T2;
    const int n0 = blockIdx.x * 64, k0 = blockIdx.y * 64;
    #pragma unroll
    for (int it = 0; it < 4; it++) {
        int k = it * 16 + (t >> 4);
        int n = (t & 15) * 4;
        float4 v = *(const float4*)(W + (size_t)(k0 + k) * DM + n0 + n);
        tile[n + 0][k] = f2bf(v.x);
        tile[n + 1][k] = f2bf(v.y);
        tile[n + 2][k] = f2bf(v.z);
        tile[n + 3][k] = f2bf(v.w);
    }
    __syncthreads();
    int n = t >> 2, kg = (t & 3) * 16;
    uint4 a = *(const uint4*)&tile[n][kg];
    uint4 b = *(const uint4*)&tile[n][kg + 8];
    *(uint4*)(WT + (size_t)(n0 + n) * DM + k0 + kg)     = a;
    *(uint4*)(WT + (size_t)(n0 + n) * DM + k0 + kg + 8) = b;
}

__global__ __launch_bounds__(256) void prep_wt1(const float* __restrict__ W, u16* __restrict__ WT) {
    __shared__ u16 tile[64][72];
    const int t = threadIdx.x;
    const int n0 = blockIdx.x * 64, k0 = blockIdx.y * 64;
    #pragma unroll
    for (int it = 0; it < 4; it++) {
        int k = it * 16 + (t >> 4);
        int n = (t & 15) * 4;
        float4 v = *(const float4*)(W + (size_t)(k0 + k) * DM + n0 + n);
        tile[n + 0][k] = f2bf(v.x);
        tile[n + 1][k] = f2bf(v.y);
        tile[n + 2][k] = f2bf(v.z);
        tile[n + 3][k] = f2bf(v.w);
    }
    __syncthreads();
    int n = t >> 2, kg = (t & 3) * 16;
    uint4 a = *(const uint4*)&tile[n][kg];
    uint4 b = *(const uint4*)&tile[n][kg + 8];
    *(uint4*)(WT + (size_t)(n0 + n) * DM + k0 + kg)     = a;
    *(uint4*)(WT + (size_t)(n0 + n) * DM + k0 + kg + 8) = b;
}

// ---- QKV projection, z-split: blockIdx.z selects Q/K/V. 128x128 tile,
// ---- BK=64, 4 waves each computing 64x64. 3 blocks/CU. (R24-exact) ----
__global__ __launch_bounds__(256, 3) void gemm_qkv_z(
    const u16* __restrict__ WQT, const u16* __restrict__ WKT, const u16* __restrict__ WVT,
    const u16* __restrict__ X,
    const float* __restrict__ bq, const float* __restrict__ bk, const float* __restrict__ bv,
    u16* __restrict__ outQ, u16* __restrict__ outK, u16* __restrict__ outVT)
{
    __shared__ u16 Ws[128][72];
    __shared__ u16 Xs[128][72];

    const int z = blockIdx.z;
    const u16* WT = (z == 0) ? WQT : (z == 1) ? WKT : WVT;

    const int t = threadIdx.x;
    const int w = t >> 6, lane = t & 63, quad = lane >> 4, l16 = lane & 15;
    const int Mb0 = blockIdx.x * 128;
    const int Nb0 = blockIdx.y * 128;
    const int mloc = (w & 1) * 64, nloc = (w >> 1) * 64;

    f32x4 acc[4][4];
    #pragma unroll
    for (int i = 0; i < 4; i++)
        #pragma unroll
        for (int j = 0; j < 4; j++) acc[i][j] = (f32x4){0.f, 0.f, 0.f, 0.f};

    const int sr = t >> 3, sc8 = (t & 7) * 8;

    for (int k0 = 0; k0 < DM; k0 += 64) {
        __syncthreads();
        #pragma unroll
        for (int i = 0; i < 4; i++) {
            int r = i * 32 + sr;
            *(uint4*)&Ws[r][sc8] = *(const uint4*)(WT + (size_t)(Mb0 + r) * DM + k0 + sc8);
            *(uint4*)&Xs[r][sc8] = *(const uint4*)(X  + (size_t)(Nb0 + r) * DM + k0 + sc8);
        }
        __syncthreads();

        #pragma unroll
        for (int ks = 0; ks < 2; ks++) {
            const int kk = ks * 32 + quad * 8;
            bf16x8 af[4], bf[4];
            #pragma unroll
            for (int mt = 0; mt < 4; mt++)
                af[mt] = *(const bf16x8*)&Ws[mloc + mt * 16 + l16][kk];
            #pragma unroll
            for (int nt = 0; nt < 4; nt++)
                bf[nt] = *(const bf16x8*)&Xs[nloc + nt * 16 + l16][kk];
            #pragma unroll
            for (int mt = 0; mt < 4; mt++)
                #pragma unroll
                for (int nt = 0; nt < 4; nt++)
                    acc[mt][nt] = __builtin_amdgcn_mfma_f32_16x16x32_bf16(af[mt], bf[nt], acc[mt][nt], 0, 0, 0);
        }
    }

    const float QS = 0.18033688f;  // 0.125 * log2(e): attn uses raw v_exp (2^x)
    if (z <= 1) {
        u16* outP = (z == 0) ? outQ : outK;
        const float* bias = (z == 0) ? bq : bk;
        const float scale = (z == 0) ? QS : 1.0f;
        #pragma unroll
        for (int mt = 0; mt < 4; mt++) {
            int nf0 = Mb0 + mloc + mt * 16 + quad * 4;
            int hh = nf0 >> 6, hd = nf0 & 63;
            float4 bb = *(const float4*)(bias + nf0);
            #pragma unroll
            for (int nt = 0; nt < 4; nt++) {
                int m = Nb0 + nloc + nt * 16 + l16;
                int b = m >> 11, s = m & 2047;
                size_t idx = (size_t)(b * NH + hh) * 131072 + (size_t)s * 64 + hd;
                *(uint2*)(outP + idx) = make_uint2(
                    pk_bf16((acc[mt][nt][0] + bb.x) * scale, (acc[mt][nt][1] + bb.y) * scale),
                    pk_bf16((acc[mt][nt][2] + bb.z) * scale, (acc[mt][nt][3] + bb.w) * scale));
            }
        }
    } else {
        #pragma unroll
        for (int mt = 0; mt < 4; mt++) {
            #pragma unroll
            for (int r = 0; r < 4; r++) {
                int nf = Mb0 + mloc + mt * 16 + quad * 4 + r;
                int hh = nf >> 6, hd = nf & 63;
                float bb = bv[nf];
                #pragma unroll
                for (int nt = 0; nt < 4; nt++) {
                    int m = Nb0 + nloc + nt * 16 + l16;
                    int b = m >> 11, s = m & 2047;
                    outVT[(size_t)(b * NH + hh) * 131072 + (size_t)hd * S_LEN + s]
                        = f2bf(acc[mt][nt][r] + bb);
                }
            }
        }
    }
}

// ---- out GEMM, LDS-staged. Block: 64 feat x 128 tok, BK=64. (R24-exact) ----
__global__ __launch_bounds__(256) void gemm_out(
    const u16* __restrict__ A, const u16* __restrict__ B,
    const float* __restrict__ bias, float* __restrict__ of32)
{
    __shared__ u16 As[64][72];
    __shared__ u16 Bs[128][72];

    const int t = threadIdx.x;
    const int w = t >> 6, lane = t & 63, quad = lane >> 4, l16 = lane & 15;
    const int Mb0 = blockIdx.x * 64;
    const int Nb0 = blockIdx.y * 128;
    const int Mb = Mb0 + (w & 1) * 32;
    const int Nb = Nb0 + (w >> 1) * 64;
    const int mloc = (w & 1) * 32, nloc = (w >> 1) * 64;

    f32x4 acc[2][4];
    #pragma unroll
    for (int i = 0; i < 2; i++)
        #pragma unroll
        for (int j = 0; j < 4; j++) acc[i][j] = (f32x4){0.f, 0.f, 0.f, 0.f};

    const int sr = t >> 3, sc8 = (t & 7) * 8;

    for (int k0 = 0; k0 < DM; k0 += 64) {
        const int h = k0 >> 6;
        __syncthreads();
        #pragma unroll
        for (int i = 0; i < 2; i++) {
            int r = i * 32 + sr;
            *(uint4*)&As[r][sc8] = *(const uint4*)(A + (size_t)(Mb0 + r) * DM + k0 + sc8);
        }
        #pragma unroll
        for (int i = 0; i < 4; i++) {
            int r = i * 32 + sr;
            int m = Nb0 + r;
            int b = m >> 11, s = m & 2047;
            *(uint4*)&Bs[r][sc8] =
                *(const uint4*)(B + (size_t)(b * NH + h) * 131072 + (size_t)s * 64 + sc8);
        }
        __syncthreads();

        #pragma unroll
        for (int ks = 0; ks < 2; ks++) {
            const int kk = ks * 32 + quad * 8;
            bf16x8 a0 = *(const bf16x8*)&As[mloc + l16][kk];
            bf16x8 a1 = *(const bf16x8*)&As[mloc + 16 + l16][kk];
            #pragma unroll
            for (int nt = 0; nt < 4; nt++) {
                bf16x8 bf = *(const bf16x8*)&Bs[nloc + nt * 16 + l16][kk];
                acc[0][nt] = __builtin_amdgcn_mfma_f32_16x16x32_bf16(a0, bf, acc[0][nt], 0, 0, 0);
                acc[1][nt] = __builtin_amdgcn_mfma_f32_16x16x32_bf16(a1, bf, acc[1][nt], 0, 0, 0);
            }
        }
    }
    #pragma unroll
    for (int mt = 0; mt < 2; mt++) {
        int nf0 = Mb + mt * 16 + quad * 4;
        float4 bvv = *(const float4*)(bias + nf0);
        #pragma unroll
        for (int nt = 0; nt < 4; nt++) {
            int m = Nb + nt * 16 + l16;
            float4 o;
            o.x = acc[mt][nt][0] + bvv.x; o.y = acc[mt][nt][1] + bvv.y;
            o.z = acc[mt][nt][2] + bvv.z; o.w = acc[mt][nt][3] + bvv.w;
            *(float4*)(of32 + (size_t)m * DM + nf0) = o;
        }
    }
}

// ---- attention: in-block split-K (R24-exact, no swizzle). ----
__global__ __launch_bounds__(512, 4) void attn_mfma(
    const u16* __restrict__ Q, const u16* __restrict__ K, const u16* __restrict__ VT,
    u16* __restrict__ O)
{
    __shared__ __align__(64) u16 smem[2][2][2][64][72];

    const int t = threadIdx.x;
    const int w = t >> 6, lane = t & 63;
    const int wq = w & 3, half = w >> 2;
    const int l32 = lane & 31, h = lane >> 5;
    const int bh = blockIdx.y;
    const int q0 = blockIdx.x * 128;
    const size_t base = (size_t)bh * 131072;

    const int qrow = q0 + wq * 32 + l32;
    bf16x8 qf[4];
    #pragma unroll
    for (int ks = 0; ks < 4; ks++)
        qf[ks] = *(const bf16x8*)(Q + base + (size_t)qrow * 64 + ks * 16 + h * 8);

    const short onebf = (short)0x3F80;
    const bf16x8 ones = {onebf, onebf, onebf, onebf, onebf, onebf, onebf, onebf};

    f32x16 o[2], lacc;
    #pragma unroll
    for (int ht = 0; ht < 2; ht++)
        #pragma unroll
        for (int i = 0; i < 16; i++) o[ht][i] = 0.f;
    #pragma unroll
    for (int i = 0; i < 16; i++) lacc[i] = 0.f;

    const int sr = t >> 3;            // 0..63
    const int sc8 = (t & 7) * 8;      // u16 col
    const u16* Kg = K + base;
    const u16* Vg = VT + base;

    *(uint4*)&smem[0][0][0][sr][sc8] = *(const uint4*)(Kg + (size_t)sr * 64 + sc8);
    *(uint4*)&smem[0][1][0][sr][sc8] = *(const uint4*)(Kg + (size_t)(16 * 64 + sr) * 64 + sc8);
    *(uint4*)&smem[1][0][0][sr][sc8] = *(const uint4*)(Vg + (size_t)sr * S_LEN + sc8);
    *(uint4*)&smem[1][1][0][sr][sc8] = *(const uint4*)(Vg + (size_t)sr * S_LEN + 16 * 64 + sc8);
    __syncthreads();

    for (int it = 0; it < 16; it++) {
        const int cur = it & 1;
        uint4 kra, krb, vra, vrb;
        if (it < 15) {
            kra = *(const uint4*)(Kg + (size_t)((it + 1) * 64 + sr) * 64 + sc8);
            krb = *(const uint4*)(Kg + (size_t)((it + 17) * 64 + sr) * 64 + sc8);
            vra = *(const uint4*)(Vg + (size_t)sr * S_LEN + (it + 1) * 64 + sc8);
            vrb = *(const uint4*)(Vg + (size_t)sr * S_LEN + (it + 17) * 64 + sc8);
        }

        const u16 (*Ksc)[72] = smem[0][half][cur];
        const u16 (*Vsc)[72] = smem[1][half][cur];

        #pragma unroll
        for (int kh = 0; kh < 2; kh++) {
            f32x16 s;
            #pragma unroll
            for (int i = 0; i < 16; i++) s[i] = 0.f;
            #pragma unroll
            for (int ks = 0; ks < 4; ks++) {
                bf16x8 kf = *(const bf16x8*)&Ksc[kh * 32 + l32][ks * 16 + h * 8];
                s = __builtin_amdgcn_mfma_f32_32x32x16_bf16(kf, qf[ks], s, 0, 0, 0);
            }
            float p[16];
            #pragma unroll
            for (int i = 0; i < 16; i++) p[i] = __builtin_amdgcn_exp2f(s[i]);
            u32 A0 = pk_bf16(p[0],  p[1]),  B0 = pk_bf16(p[2],  p[3]);
            u32 A1 = pk_bf16(p[4],  p[5]),  B1 = pk_bf16(p[6],  p[7]);
            u32 A2 = pk_bf16(p[8],  p[9]),  B2 = pk_bf16(p[10], p[11]);
            u32 A3 = pk_bf16(p[12], p[13]), B3 = pk_bf16(p[14], p[15]);
            u32x2 sA0 = __builtin_amdgcn_permlane32_swap(A0, A1, false, false);
            u32x2 sB0 = __builtin_amdgcn_permlane32_swap(B0, B1, false, false);
            u32x2 sA1 = __builtin_amdgcn_permlane32_swap(A2, A3, false, false);
            u32x2 sB1 = __builtin_amdgcn_permlane32_swap(B2, B3, false, false);
            union { bf16x8 v; u32 wd[4]; } fr0, fr1;
            fr0.wd[0] = sA0.x; fr0.wd[1] = sB0.x; fr0.wd[2] = sA0.y; fr0.wd[3] = sB0.y;
            fr1.wd[0] = sA1.x; fr1.wd[1] = sB1.x; fr1.wd[2] = sA1.y; fr1.wd[3] = sB1.y;

            lacc = __builtin_amdgcn_mfma_f32_32x32x16_bf16(fr0.v, ones, lacc, 0, 0, 0);
            lacc = __builtin_amdgcn_mfma_f32_32x32x16_bf16(fr1.v, ones, lacc, 0, 0, 0);

            #pragma unroll
            for (int ht = 0; ht < 2; ht++) {
                bf16x8 vf0 = *(const bf16x8*)&Vsc[ht * 32 + l32][kh * 32 + h * 8];
                o[ht] = __builtin_amdgcn_mfma_f32_32x32x16_bf16(fr0.v, vf0, o[ht], 0, 0, 0);
                bf16x8 vf1 = *(const bf16x8*)&Vsc[ht * 32 + l32][kh * 32 + 16 + h * 8];
                o[ht] = __builtin_amdgcn_mfma_f32_32x32x16_bf16(fr1.v, vf1, o[ht], 0, 0, 0);
            }
        }

        if (it < 15) {
            *(uint4*)&smem[0][0][cur ^ 1][sr][sc8] = kra;
            *(uint4*)&smem[0][1][cur ^ 1][sr][sc8] = krb;
            *(uint4*)&smem[1][0][cur ^ 1][sr][sc8] = vra;
            *(uint4*)&smem[1][1][cur ^ 1][sr][sc8] = vrb;
        }
        __syncthreads();
    }

    float* red = (float*)&smem[0][0][0][0][0];
    if (half) {
        #pragma unroll
        for (int i = 0; i < 16; i++) {
            red[((0 + wq) * 16 + i) * 64 + lane] = o[0][i];
            red[((4 + wq) * 16 + i) * 64 + lane] = o[1][i];
            red[((8 + wq) * 16 + i) * 64 + lane] = lacc[i];
        }
    }
    __syncthreads();
    if (!half) {
        #pragma unroll
        for (int i = 0; i < 16; i++) {
            o[0][i] += red[((0 + wq) * 16 + i) * 64 + lane];
            o[1][i] += red[((4 + wq) * 16 + i) * 64 + lane];
            lacc[i] += red[((8 + wq) * 16 + i) * 64 + lane];
        }
        float inv[16];
        #pragma unroll
        for (int r = 0; r < 16; r++) inv[r] = 1.0f / lacc[r];
        #pragma unroll
        for (int ht = 0; ht < 2; ht++)
            #pragma unroll
            for (int r = 0; r < 16; r++) {
                int q = q0 + wq * 32 + (r & 3) + 8 * (r >> 2) + 4 * h;
                O[base + (size_t)q * 64 + ht * 32 + l32] = f2bf(o[ht][r] * inv[r]);
            }
    }
}

extern "C" void kernel_launch(void* const* d_in, const int* in_sizes, int n_in,
                              void* d_out, int out_size, void* d_ws, size_t ws_size,
                              hipStream_t stream) {
    const float* x  = (const float*)d_in[0];
    const float* Wq = (const float*)d_in[1];
    const float* bq = (const float*)d_in[2];
    const float* Wk = (const float*)d_in[3];
    const float* bk = (const float*)d_in[4];
    const float* Wv = (const float*)d_in[5];
    const float* bv = (const float*)d_in[6];
    const float* Wo = (const float*)d_in[7];
    const float* bo = (const float*)d_in[8];
    float* out = (float*)d_out;

    // d_out as scratch during prep+proj (dead until final GEMM)
    u16* xbf = (u16*)d_out;
    u16* wqt = xbf + 4194304;
    u16* wkt = wqt + 1048576;
    u16* wvt = wkt + 1048576;

    u16* qws  = (u16*)d_ws;               // Q, later attnout (head layout)
    u16* kws  = qws + 4194304;            // K head layout; later Wo^T
    u16* vtws = kws + 4194304;            // V^T [bh][hd][s]
    u16* wot  = kws;

    prep_all<<<dim3(16, 16, 5), 256, 0, stream>>>(Wq, Wk, Wv, x, wqt, wkt, wvt, xbf);

    gemm_qkv_z<<<dim3(8, 32, 3), 256, 0, stream>>>(wqt, wkt, wvt, xbf, bq, bk, bv,
                                                   qws, kws, vtws);

    attn_mfma<<<dim3(16, 32), 512, 0, stream>>>(qws, kws, vtws, qws);

    prep_wt1<<<dim3(16, 16), 256, 0, stream>>>(Wo, wot);
    gemm_out<<<dim3(16, 32), 256, 0, stream>>>(wot, qws, bo, out);
}

// Round 20
// 193.951 us; speedup vs baseline: 1.0370x; 1.0124x over previous
//
#include <hip/hip_runtime.h>
#include <hip/hip_bf16.h>
#include <string.h>

// MHA B=2,S=2048,D=1024,H=16,Hd=64. Inputs fp32, output fp32.
// R30 (3rd resubmit; R18/R19 benches were GPU-acquisition infra failures,
// kernel never ran). R29 (196.3us measured, session best) + last
// launch-merge rung: if ws_size fits Q/K/VT/WoT without aliasing
// (>=27,262,976 B), Wo^T moves out of kws and its transpose folds into
// prep_all (z=5), dropping prep_wt1 from between attn and gemm_out ->
// 4 launches, gap-free attn->gemm_out handoff. Host-side ws_size check
// (graph-safe); fallback = R29-exact. Compute kernels bit-identical to
// R24/R29.

#define DM 1024
#define S_LEN 2048
#define NH 16
#define HD 64

using u16 = unsigned short;
using u32 = unsigned int;

typedef short bf16x8 __attribute__((ext_vector_type(8)));
typedef float f32x4  __attribute__((ext_vector_type(4)));
typedef float f32x16 __attribute__((ext_vector_type(16)));
typedef unsigned int u32x2 __attribute__((ext_vector_type(2)));

__device__ __forceinline__ u16 f2bf(float f) {
    u32 i = __float_as_uint(f);
    u32 r = i + 0x7fffu + ((i >> 16) & 1u);  // RNE
    return (u16)(r >> 16);
}
__device__ __forceinline__ u32 pk_bf16(float a, float b) {  // low16=a, high16=b (RNE)
    __hip_bfloat162 h = __float22bfloat162_rn(float2{a, b});
    u32 r; memcpy(&r, &h, 4);
    return r;
}

__device__ __forceinline__ void wt_tile(const float* __restrict__ W, u16* __restrict__ WT,
                                        int n0, int k0, int t, u16 (*tile)[72]) {
    #pragma unroll
    for (int it = 0; it < 4; it++) {
        int k = it * 16 + (t >> 4);
        int n = (t & 15) * 4;
        float4 v = *(const float4*)(W + (size_t)(k0 + k) * DM + n0 + n);
        tile[n + 0][k] = f2bf(v.x);
        tile[n + 1][k] = f2bf(v.y);
        tile[n + 2][k] = f2bf(v.z);
        tile[n + 3][k] = f2bf(v.w);
    }
    __syncthreads();
    int n = t >> 2, kg = (t & 3) * 16;
    uint4 a = *(const uint4*)&tile[n][kg];
    uint4 b = *(const uint4*)&tile[n][kg + 8];
    *(uint4*)(WT + (size_t)(n0 + n) * DM + k0 + kg)     = a;
    *(uint4*)(WT + (size_t)(n0 + n) * DM + k0 + kg + 8) = b;
}

// ---- merged prep: z=0..2 Wq/Wk/Wv transpose; z=3..4 x convert;
// ---- z=5 (only when launched with gridDim.z==6) Wo transpose ----
__global__ __launch_bounds__(256) void prep_all(
    const float* __restrict__ W0, const float* __restrict__ W1, const float* __restrict__ W2,
    const float* __restrict__ W3, const float* __restrict__ X,
    u16* __restrict__ T0, u16* __restrict__ T1, u16* __restrict__ T2,
    u16* __restrict__ T3, u16* __restrict__ xout)
{
    __shared__ u16 tile[64][72];
    const int z = blockIdx.z;
    const int t = threadIdx.x;

    if (z == 3 || z == 4) {
        // x fp32 -> bf16: 512 blocks x 256 thr x 4 elems x 8 iters = 4,194,304
        const int lin = ((z - 3) * 16 + blockIdx.y) * 16 + blockIdx.x;  // [0,512)
        const int base = (lin * 256 + t) * 4;
        #pragma unroll
        for (int i = 0; i < 8; i++) {
            int idx = base + i * 524288;
            float4 v = *(const float4*)(X + idx);
            *(uint2*)(xout + idx) = make_uint2(pk_bf16(v.x, v.y), pk_bf16(v.z, v.w));
        }
        return;
    }

    const float* W = (z == 0) ? W0 : (z == 1) ? W1 : (z == 2) ? W2 : W3;
    u16* WT        = (z == 0) ? T0 : (z == 1) ? T1 : (z == 2) ? T2 : T3;
    wt_tile(W, WT, blockIdx.x * 64, blockIdx.y * 64, t, tile);
}

__global__ __launch_bounds__(256) void prep_wt1(const float* __restrict__ W, u16* __restrict__ WT) {
    __shared__ u16 tile[64][72];
    wt_tile(W, WT, blockIdx.x * 64, blockIdx.y * 64, threadIdx.x, tile);
}

// ---- QKV projection, z-split: blockIdx.z selects Q/K/V. 128x128 tile,
// ---- BK=64, 4 waves each computing 64x64. 3 blocks/CU. (R24-exact) ----
__global__ __launch_bounds__(256, 3) void gemm_qkv_z(
    const u16* __restrict__ WQT, const u16* __restrict__ WKT, const u16* __restrict__ WVT,
    const u16* __restrict__ X,
    const float* __restrict__ bq, const float* __restrict__ bk, const float* __restrict__ bv,
    u16* __restrict__ outQ, u16* __restrict__ outK, u16* __restrict__ outVT)
{
    __shared__ u16 Ws[128][72];
    __shared__ u16 Xs[128][72];

    const int z = blockIdx.z;
    const u16* WT = (z == 0) ? WQT : (z == 1) ? WKT : WVT;

    const int t = threadIdx.x;
    const int w = t >> 6, lane = t & 63, quad = lane >> 4, l16 = lane & 15;
    const int Mb0 = blockIdx.x * 128;
    const int Nb0 = blockIdx.y * 128;
    const int mloc = (w & 1) * 64, nloc = (w >> 1) * 64;

    f32x4 acc[4][4];
    #pragma unroll
    for (int i = 0; i < 4; i++)
        #pragma unroll
        for (int j = 0; j < 4; j++) acc[i][j] = (f32x4){0.f, 0.f, 0.f, 0.f};

    const int sr = t >> 3, sc8 = (t & 7) * 8;

    for (int k0 = 0; k0 < DM; k0 += 64) {
        __syncthreads();
        #pragma unroll
        for (int i = 0; i < 4; i++) {
            int r = i * 32 + sr;
            *(uint4*)&Ws[r][sc8] = *(const uint4*)(WT + (size_t)(Mb0 + r) * DM + k0 + sc8);
            *(uint4*)&Xs[r][sc8] = *(const uint4*)(X  + (size_t)(Nb0 + r) * DM + k0 + sc8);
        }
        __syncthreads();

        #pragma unroll
        for (int ks = 0; ks < 2; ks++) {
            const int kk = ks * 32 + quad * 8;
            bf16x8 af[4], bf[4];
            #pragma unroll
            for (int mt = 0; mt < 4; mt++)
                af[mt] = *(const bf16x8*)&Ws[mloc + mt * 16 + l16][kk];
            #pragma unroll
            for (int nt = 0; nt < 4; nt++)
                bf[nt] = *(const bf16x8*)&Xs[nloc + nt * 16 + l16][kk];
            #pragma unroll
            for (int mt = 0; mt < 4; mt++)
                #pragma unroll
                for (int nt = 0; nt < 4; nt++)
                    acc[mt][nt] = __builtin_amdgcn_mfma_f32_16x16x32_bf16(af[mt], bf[nt], acc[mt][nt], 0, 0, 0);
        }
    }

    const float QS = 0.18033688f;  // 0.125 * log2(e): attn uses raw v_exp (2^x)
    if (z <= 1) {
        u16* outP = (z == 0) ? outQ : outK;
        const float* bias = (z == 0) ? bq : bk;
        const float scale = (z == 0) ? QS : 1.0f;
        #pragma unroll
        for (int mt = 0; mt < 4; mt++) {
            int nf0 = Mb0 + mloc + mt * 16 + quad * 4;
            int hh = nf0 >> 6, hd = nf0 & 63;
            float4 bb = *(const float4*)(bias + nf0);
            #pragma unroll
            for (int nt = 0; nt < 4; nt++) {
                int m = Nb0 + nloc + nt * 16 + l16;
                int b = m >> 11, s = m & 2047;
                size_t idx = (size_t)(b * NH + hh) * 131072 + (size_t)s * 64 + hd;
                *(uint2*)(outP + idx) = make_uint2(
                    pk_bf16((acc[mt][nt][0] + bb.x) * scale, (acc[mt][nt][1] + bb.y) * scale),
                    pk_bf16((acc[mt][nt][2] + bb.z) * scale, (acc[mt][nt][3] + bb.w) * scale));
            }
        }
    } else {
        #pragma unroll
        for (int mt = 0; mt < 4; mt++) {
            #pragma unroll
            for (int r = 0; r < 4; r++) {
                int nf = Mb0 + mloc + mt * 16 + quad * 4 + r;
                int hh = nf >> 6, hd = nf & 63;
                float bb = bv[nf];
                #pragma unroll
                for (int nt = 0; nt < 4; nt++) {
                    int m = Nb0 + nloc + nt * 16 + l16;
                    int b = m >> 11, s = m & 2047;
                    outVT[(size_t)(b * NH + hh) * 131072 + (size_t)hd * S_LEN + s]
                        = f2bf(acc[mt][nt][r] + bb);
                }
            }
        }
    }
}

// ---- out GEMM, LDS-staged. Block: 64 feat x 128 tok, BK=64. (R24-exact) ----
__global__ __launch_bounds__(256) void gemm_out(
    const u16* __restrict__ A, const u16* __restrict__ B,
    const float* __restrict__ bias, float* __restrict__ of32)
{
    __shared__ u16 As[64][72];
    __shared__ u16 Bs[128][72];

    const int t = threadIdx.x;
    const int w = t >> 6, lane = t & 63, quad = lane >> 4, l16 = lane & 15;
    const int Mb0 = blockIdx.x * 64;
    const int Nb0 = blockIdx.y * 128;
    const int Mb = Mb0 + (w & 1) * 32;
    const int Nb = Nb0 + (w >> 1) * 64;
    const int mloc = (w & 1) * 32, nloc = (w >> 1) * 64;

    f32x4 acc[2][4];
    #pragma unroll
    for (int i = 0; i < 2; i++)
        #pragma unroll
        for (int j = 0; j < 4; j++) acc[i][j] = (f32x4){0.f, 0.f, 0.f, 0.f};

    const int sr = t >> 3, sc8 = (t & 7) * 8;

    for (int k0 = 0; k0 < DM; k0 += 64) {
        const int h = k0 >> 6;
        __syncthreads();
        #pragma unroll
        for (int i = 0; i < 2; i++) {
            int r = i * 32 + sr;
            *(uint4*)&As[r][sc8] = *(const uint4*)(A + (size_t)(Mb0 + r) * DM + k0 + sc8);
        }
        #pragma unroll
        for (int i = 0; i < 4; i++) {
            int r = i * 32 + sr;
            int m = Nb0 + r;
            int b = m >> 11, s = m & 2047;
            *(uint4*)&Bs[r][sc8] =
                *(const uint4*)(B + (size_t)(b * NH + h) * 131072 + (size_t)s * 64 + sc8);
        }
        __syncthreads();

        #pragma unroll
        for (int ks = 0; ks < 2; ks++) {
            const int kk = ks * 32 + quad * 8;
            bf16x8 a0 = *(const bf16x8*)&As[mloc + l16][kk];
            bf16x8 a1 = *(const bf16x8*)&As[mloc + 16 + l16][kk];
            #pragma unroll
            for (int nt = 0; nt < 4; nt++) {
                bf16x8 bf = *(const bf16x8*)&Bs[nloc + nt * 16 + l16][kk];
                acc[0][nt] = __builtin_amdgcn_mfma_f32_16x16x32_bf16(a0, bf, acc[0][nt], 0, 0, 0);
                acc[1][nt] = __builtin_amdgcn_mfma_f32_16x16x32_bf16(a1, bf, acc[1][nt], 0, 0, 0);
            }
        }
    }
    #pragma unroll
    for (int mt = 0; mt < 2; mt++) {
        int nf0 = Mb + mt * 16 + quad * 4;
        float4 bvv = *(const float4*)(bias + nf0);
        #pragma unroll
        for (int nt = 0; nt < 4; nt++) {
            int m = Nb + nt * 16 + l16;
            float4 o;
            o.x = acc[mt][nt][0] + bvv.x; o.y = acc[mt][nt][1] + bvv.y;
            o.z = acc[mt][nt][2] + bvv.z; o.w = acc[mt][nt][3] + bvv.w;
            *(float4*)(of32 + (size_t)m * DM + nf0) = o;
        }
    }
}

// ---- attention: in-block split-K (R24-exact, no swizzle). ----
__global__ __launch_bounds__(512, 4) void attn_mfma(
    const u16* __restrict__ Q, const u16* __restrict__ K, const u16* __restrict__ VT,
    u16* __restrict__ O)
{
    __shared__ __align__(64) u16 smem[2][2][2][64][72];

    const int t = threadIdx.x;
    const int w = t >> 6, lane = t & 63;
    const int wq = w & 3, half = w >> 2;
    const int l32 = lane & 31, h = lane >> 5;
    const int bh = blockIdx.y;
    const int q0 = blockIdx.x * 128;
    const size_t base = (size_t)bh * 131072;

    const int qrow = q0 + wq * 32 + l32;
    bf16x8 qf[4];
    #pragma unroll
    for (int ks = 0; ks < 4; ks++)
        qf[ks] = *(const bf16x8*)(Q + base + (size_t)qrow * 64 + ks * 16 + h * 8);

    const short onebf = (short)0x3F80;
    const bf16x8 ones = {onebf, onebf, onebf, onebf, onebf, onebf, onebf, onebf};

    f32x16 o[2], lacc;
    #pragma unroll
    for (int ht = 0; ht < 2; ht++)
        #pragma unroll
        for (int i = 0; i < 16; i++) o[ht][i] = 0.f;
    #pragma unroll
    for (int i = 0; i < 16; i++) lacc[i] = 0.f;

    const int sr = t >> 3;            // 0..63
    const int sc8 = (t & 7) * 8;      // u16 col
    const u16* Kg = K + base;
    const u16* Vg = VT + base;

    *(uint4*)&smem[0][0][0][sr][sc8] = *(const uint4*)(Kg + (size_t)sr * 64 + sc8);
    *(uint4*)&smem[0][1][0][sr][sc8] = *(const uint4*)(Kg + (size_t)(16 * 64 + sr) * 64 + sc8);
    *(uint4*)&smem[1][0][0][sr][sc8] = *(const uint4*)(Vg + (size_t)sr * S_LEN + sc8);
    *(uint4*)&smem[1][1][0][sr][sc8] = *(const uint4*)(Vg + (size_t)sr * S_LEN + 16 * 64 + sc8);
    __syncthreads();

    for (int it = 0; it < 16; it++) {
        const int cur = it & 1;
        uint4 kra, krb, vra, vrb;
        if (it < 15) {
            kra = *(const uint4*)(Kg + (size_t)((it + 1) * 64 + sr) * 64 + sc8);
            krb = *(const uint4*)(Kg + (size_t)((it + 17) * 64 + sr) * 64 + sc8);
            vra = *(const uint4*)(Vg + (size_t)sr * S_LEN + (it + 1) * 64 + sc8);
            vrb = *(const uint4*)(Vg + (size_t)sr * S_LEN + (it + 17) * 64 + sc8);
        }

        const u16 (*Ksc)[72] = smem[0][half][cur];
        const u16 (*Vsc)[72] = smem[1][half][cur];

        #pragma unroll
        for (int kh = 0; kh < 2; kh++) {
            f32x16 s;
            #pragma unroll
            for (int i = 0; i < 16; i++) s[i] = 0.f;
            #pragma unroll
            for (int ks = 0; ks < 4; ks++) {
                bf16x8 kf = *(const bf16x8*)&Ksc[kh * 32 + l32][ks * 16 + h * 8];
                s = __builtin_amdgcn_mfma_f32_32x32x16_bf16(kf, qf[ks], s, 0, 0, 0);
            }
            float p[16];
            #pragma unroll
            for (int i = 0; i < 16; i++) p[i] = __builtin_amdgcn_exp2f(s[i]);
            u32 A0 = pk_bf16(p[0],  p[1]),  B0 = pk_bf16(p[2],  p[3]);
            u32 A1 = pk_bf16(p[4],  p[5]),  B1 = pk_bf16(p[6],  p[7]);
            u32 A2 = pk_bf16(p[8],  p[9]),  B2 = pk_bf16(p[10], p[11]);
            u32 A3 = pk_bf16(p[12], p[13]), B3 = pk_bf16(p[14], p[15]);
            u32x2 sA0 = __builtin_amdgcn_permlane32_swap(A0, A1, false, false);
            u32x2 sB0 = __builtin_amdgcn_permlane32_swap(B0, B1, false, false);
            u32x2 sA1 = __builtin_amdgcn_permlane32_swap(A2, A3, false, false);
            u32x2 sB1 = __builtin_amdgcn_permlane32_swap(B2, B3, false, false);
            union { bf16x8 v; u32 wd[4]; } fr0, fr1;
            fr0.wd[0] = sA0.x; fr0.wd[1] = sB0.x; fr0.wd[2] = sA0.y; fr0.wd[3] = sB0.y;
            fr1.wd[0] = sA1.x; fr1.wd[1] = sB1.x; fr1.wd[2] = sA1.y; fr1.wd[3] = sB1.y;

            lacc = __builtin_amdgcn_mfma_f32_32x32x16_bf16(fr0.v, ones, lacc, 0, 0, 0);
            lacc = __builtin_amdgcn_mfma_f32_32x32x16_bf16(fr1.v, ones, lacc, 0, 0, 0);

            #pragma unroll
            for (int ht = 0; ht < 2; ht++) {
                bf16x8 vf0 = *(const bf16x8*)&Vsc[ht * 32 + l32][kh * 32 + h * 8];
                o[ht] = __builtin_amdgcn_mfma_f32_32x32x16_bf16(fr0.v, vf0, o[ht], 0, 0, 0);
                bf16x8 vf1 = *(const bf16x8*)&Vsc[ht * 32 + l32][kh * 32 + 16 + h * 8];
                o[ht] = __builtin_amdgcn_mfma_f32_32x32x16_bf16(fr1.v, vf1, o[ht], 0, 0, 0);
            }
        }

        if (it < 15) {
            *(uint4*)&smem[0][0][cur ^ 1][sr][sc8] = kra;
            *(uint4*)&smem[0][1][cur ^ 1][sr][sc8] = krb;
            *(uint4*)&smem[1][0][cur ^ 1][sr][sc8] = vra;
            *(uint4*)&smem[1][1][cur ^ 1][sr][sc8] = vrb;
        }
        __syncthreads();
    }

    float* red = (float*)&smem[0][0][0][0][0];
    if (half) {
        #pragma unroll
        for (int i = 0; i < 16; i++) {
            red[((0 + wq) * 16 + i) * 64 + lane] = o[0][i];
            red[((4 + wq) * 16 + i) * 64 + lane] = o[1][i];
            red[((8 + wq) * 16 + i) * 64 + lane] = lacc[i];
        }
    }
    __syncthreads();
    if (!half) {
        #pragma unroll
        for (int i = 0; i < 16; i++) {
            o[0][i] += red[((0 + wq) * 16 + i) * 64 + lane];
            o[1][i] += red[((4 + wq) * 16 + i) * 64 + lane];
            lacc[i] += red[((8 + wq) * 16 + i) * 64 + lane];
        }
        float inv[16];
        #pragma unroll
        for (int r = 0; r < 16; r++) inv[r] = 1.0f / lacc[r];
        #pragma unroll
        for (int ht = 0; ht < 2; ht++)
            #pragma unroll
            for (int r = 0; r < 16; r++) {
                int q = q0 + wq * 32 + (r & 3) + 8 * (r >> 2) + 4 * h;
                O[base + (size_t)q * 64 + ht * 32 + l32] = f2bf(o[ht][r] * inv[r]);
            }
    }
}

extern "C" void kernel_launch(void* const* d_in, const int* in_sizes, int n_in,
                              void* d_out, int out_size, void* d_ws, size_t ws_size,
                              hipStream_t stream) {
    const float* x  = (const float*)d_in[0];
    const float* Wq = (const float*)d_in[1];
    const float* bq = (const float*)d_in[2];
    const float* Wk = (const float*)d_in[3];
    const float* bk = (const float*)d_in[4];
    const float* Wv = (const float*)d_in[5];
    const float* bv = (const float*)d_in[6];
    const float* Wo = (const float*)d_in[7];
    const float* bo = (const float*)d_in[8];
    float* out = (float*)d_out;

    // d_out as scratch during prep+proj (dead until final GEMM)
    u16* xbf = (u16*)d_out;
    u16* wqt = xbf + 4194304;
    u16* wkt = wqt + 1048576;
    u16* wvt = wkt + 1048576;

    u16* qws  = (u16*)d_ws;               // Q, later attnout (head layout)
    u16* kws  = qws + 4194304;            // K head layout; later Wo^T (fallback)
    u16* vtws = kws + 4194304;            // V^T [bh][hd][s]

    // merged path needs Q+K+VT+WoT = (3*4194304 + 1048576)*2 B
    const bool big_ws = ws_size >= (size_t)(3 * 4194304 + 1048576) * 2;
    u16* wot = big_ws ? (vtws + 4194304) : kws;

    if (big_ws) {
        // 4 launches: Wo transpose folded into prep_all (z=5)
        prep_all<<<dim3(16, 16, 6), 256, 0, stream>>>(Wq, Wk, Wv, Wo, x,
                                                      wqt, wkt, wvt, wot, xbf);
        gemm_qkv_z<<<dim3(8, 32, 3), 256, 0, stream>>>(wqt, wkt, wvt, xbf, bq, bk, bv,
                                                       qws, kws, vtws);
        attn_mfma<<<dim3(16, 32), 512, 0, stream>>>(qws, kws, vtws, qws);
        gemm_out<<<dim3(16, 32), 256, 0, stream>>>(wot, qws, bo, out);
    } else {
        // R29 fallback: wot aliases kws, transpose must wait for attn
        prep_all<<<dim3(16, 16, 5), 256, 0, stream>>>(Wq, Wk, Wv, Wo, x,
                                                      wqt, wkt, wvt, wot, xbf);
        gemm_qkv_z<<<dim3(8, 32, 3), 256, 0, stream>>>(wqt, wkt, wvt, xbf, bq, bk, bv,
                                                       qws, kws, vtws);
        attn_mfma<<<dim3(16, 32), 512, 0, stream>>>(qws, kws, vtws, qws);
        prep_wt1<<<dim3(16, 16), 256, 0, stream>>>(Wo, wot);
        gemm_out<<<dim3(16, 32), 256, 0, stream>>>(wot, qws, bo, out);
    }
}